// Round 6
// baseline (501.118 us; speedup 1.0000x reference)
//
#include <hip/hip_runtime.h>

#define NB    4096
#define TSTEP 256
#define DTC   0.01f

typedef float v2f __attribute__((ext_vector_type(2)));
typedef float v4f __attribute__((ext_vector_type(4)));

// tanh(a) = (E-1)/(E+1), E = exp(2a) via v_exp_f32 + v_rcp_f32 (upper clamp only:
// exp2(very negative) -> 0 -> tanh -> -1 cleanly; y can reach ~5e3 so clamp matters)
__device__ __forceinline__ float fast_tanh(float a) {
    float t = fminf(a * 2.885390082f, 126.0f);   // 2*log2(e)*a
    float E = __builtin_amdgcn_exp2f(t);
    return (E - 1.0f) * __builtin_amdgcn_rcpf(E + 1.0f);
}
// exp(a), |a| small here (dt-scaled)
__device__ __forceinline__ float fast_exp(float a) {
    return __builtin_amdgcn_exp2f(a * 1.44269504f);
}
// guaranteed packed fp32 FMA: acc = a*b + acc (2 fp32 lanes per instruction)
__device__ __forceinline__ void pk_fma(v2f& acc, v2f a, v2f b) {
    asm("v_pk_fma_f32 %0, %1, %2, %0" : "+v"(acc) : "v"(a), "v"(b));
}

__global__ void __launch_bounds__(64) __attribute__((amdgpu_waves_per_eu(3, 3)))
koopman_kernel(const float* __restrict__ x,
               const float* __restrict__ Wc1, const float* __restrict__ bc1,
               const float* __restrict__ Wc2, const float* __restrict__ bc2,
               const float* __restrict__ Wr1, const float* __restrict__ br1,
               const float* __restrict__ Wr2, const float* __restrict__ br2,
               float* __restrict__ out)
{
    const int lane = threadIdx.x;            // 0..63 = output feature
    const int blk  = blockIdx.x;             // 0..NB-1, one element per wave

    __shared__ __align__(16) float lds_y[64];
    __shared__ __align__(16) float lds_u[64];

    const bool is_c = (lane < 48);

    // ---- persistent weights as float2 pairs (SROA-friendly scalar builds) ----
    v2f w1[32], w2[24];
    float b1, b2;
    {
        const float* p1 = is_c ? (Wc1 + lane * 64) : (Wr1 + (lane - 48) * 64);
        #pragma unroll
        for (int k = 0; k < 32; ++k) {
            v2f tv; tv.x = p1[2*k]; tv.y = p1[2*k + 1]; w1[k] = tv;
        }
        const float* p2 = is_c ? (Wc2 + lane * 48) : (Wr2 + (lane - 48) * 16);
        #pragma unroll
        for (int k = 0; k < 24; ++k) {
            const bool valid = is_c || (k >= 16);          // r-lanes: only last 8 pairs real
            const int  kk    = is_c ? 2*k : (k >= 16 ? 2*k - 32 : 0);
            v2f tv; tv.x = valid ? p2[kk] : 0.0f; tv.y = valid ? p2[kk + 1] : 0.0f;
            w2[k] = tv;
        }
        b1 = is_c ? bc1[lane] : br1[lane - 48];
        b2 = is_c ? bc2[lane] : br2[lane - 48];
    }
    // layer-2 input window: c-lanes read u[0..47]; r-lanes read u[16..63] with
    // w2[0..15]=0 so only u[48..63] (their own tanh block) contributes.
    const int   ubase = is_c ? 0 : 16;
    const float sgn   = (lane & 1) ? 1.0f : -1.0f;
    const bool  odd   = (lane & 1) != 0;

    // ---- init state ----
    float ysel = x[blk * 64 + lane];
    lds_y[lane] = ysel;
    float* pout = out + (size_t)blk * (TSTEP * 64) + lane;

    // Single-wave workgroup, wave-synchronous LDS (in-order DS pipe): no barriers.
    for (int t = 0; t < TSTEP; ++t) {
        // ---- layer 1: u = tanh(W1 @ y + b1); 4 independent pk_fma chains ----
        v2f aA = {b1, 0.0f}, aB = {0.0f, 0.0f}, aC = aB, aD = aB;
        #pragma unroll
        for (int k = 0; k < 16; ++k) {
            const v4f q = *reinterpret_cast<const v4f*>(&lds_y[k * 4]);
            const v2f lo = __builtin_shufflevector(q, q, 0, 1);
            const v2f hi = __builtin_shufflevector(q, q, 2, 3);
            if (k & 1) { pk_fma(aC, w1[2*k], lo); pk_fma(aD, w1[2*k + 1], hi); }
            else       { pk_fma(aA, w1[2*k], lo); pk_fma(aB, w1[2*k + 1], hi); }
        }
        {
            const v2f s2 = (aA + aB) + (aC + aD);
            lds_u[lane] = fast_tanh(s2.x + s2.y);
        }

        // ---- layer 2: co/re = W2 @ u + b2; 4 chains ----
        v2f cA = {b2, 0.0f}, cB = {0.0f, 0.0f}, cC = cB, cD = cB;
        #pragma unroll
        for (int k = 0; k < 12; ++k) {
            const v4f q = *reinterpret_cast<const v4f*>(&lds_u[ubase + k * 4]);
            const v2f lo = __builtin_shufflevector(q, q, 0, 1);
            const v2f hi = __builtin_shufflevector(q, q, 2, 3);
            if (k & 1) { pk_fma(cC, w2[2*k], lo); pk_fma(cD, w2[2*k + 1], hi); }
            else       { pk_fma(cA, w2[2*k], lo); pk_fma(cB, w2[2*k + 1], hi); }
        }
        const v2f c2 = (cA + cB) + (cC + cD);
        const float co = c2.x + c2.y;

        // ---- pointwise update ----
        const float other = __shfl_xor(co, 1, 64);
        const float mu = odd ? other : co;     // even slot of pair
        const float om = odd ? co    : other;  // odd slot of pair
        const float scale = fast_exp(DTC * mu);
        const float omr = om * 1.59154943e-3f; // dt*om/(2*pi): v_sin takes revolutions
        const float sv = __builtin_amdgcn_sinf(omr) * scale;
        const float cv = __builtin_amdgcn_cosf(omr) * scale;
        const float yo = __shfl_xor(ysel, 1, 64);
        // even lane: c*y_self - s*y_partner ; odd lane: c*y_self + s*y_partner
        const float ycnew = fmaf(cv, ysel, sgn * sv * yo);
        const float yrnew = fast_exp(DTC * co) * ysel;
        const float ynew  = is_c ? ycnew : yrnew;
        ysel = ynew;
        lds_y[lane] = ynew;
        __builtin_nontemporal_store(ynew, pout);   // write-once 256 MB stream
        pout += 64;
    }
}

extern "C" void kernel_launch(void* const* d_in, const int* in_sizes, int n_in,
                              void* d_out, int out_size, void* d_ws, size_t ws_size,
                              hipStream_t stream) {
    const float* x   = (const float*)d_in[0];
    const float* Wc1 = (const float*)d_in[1];
    const float* bc1 = (const float*)d_in[2];
    const float* Wc2 = (const float*)d_in[3];
    const float* bc2 = (const float*)d_in[4];
    const float* Wr1 = (const float*)d_in[5];
    const float* br1 = (const float*)d_in[6];
    const float* Wr2 = (const float*)d_in[7];
    const float* br2 = (const float*)d_in[8];
    float* out = (float*)d_out;

    koopman_kernel<<<dim3(NB), dim3(64), 0, stream>>>(
        x, Wc1, bc1, Wc2, bc2, Wr1, br1, Wr2, br2, out);
}

// Round 7
// 235.177 us; speedup vs baseline: 2.1308x; 2.1308x over previous
//
#include <hip/hip_runtime.h>

#define NB    4096
#define TSTEP 256
#define DTC   0.01f

typedef _Float16 h2 __attribute__((ext_vector_type(2)));
typedef _Float16 h8 __attribute__((ext_vector_type(8)));

// tanh(a) = (E-1)/(E+1), E = exp(2a) via v_exp_f32 + v_rcp_f32.
// Upper clamp required: |a| reaches ~5e3 here -> exp2 would overflow -> NaN.
__device__ __forceinline__ float fast_tanh(float a) {
    float t = fminf(a * 2.885390082f, 126.0f);   // 2*log2(e)*a
    float E = __builtin_amdgcn_exp2f(t);
    return (E - 1.0f) * __builtin_amdgcn_rcpf(E + 1.0f);
}
// exp(a) for small |a| (dt-scaled, |a| <~ 0.5)
__device__ __forceinline__ float fast_exp(float a) {
    return __builtin_amdgcn_exp2f(a * 1.44269504f);
}

__global__ void __launch_bounds__(64) __attribute__((amdgpu_waves_per_eu(4, 4)))
koopman_kernel(const float* __restrict__ x,
               const float* __restrict__ Wc1, const float* __restrict__ bc1,
               const float* __restrict__ Wc2, const float* __restrict__ bc2,
               const float* __restrict__ Wr1, const float* __restrict__ br1,
               const float* __restrict__ Wr2, const float* __restrict__ br2,
               float* __restrict__ out)
{
    const int lane = threadIdx.x;            // 0..63 = output feature
    const int blk  = blockIdx.x;             // 0..NB-1, one element per wave

    // broadcast copies of y and u live in LDS as f16 (recurrent state stays fp32)
    __shared__ __align__(16) h8 lds_y8[8];   // 64 feats as f16
    __shared__ __align__(16) h8 lds_u8[8];

    const bool is_c = (lane < 48);

    // ---- persistent weights, f16-packed: 56 VGPRs total ----
    h2 w1p[32], w2p[24];
    float b1, b2;
    {
        const float* p1 = is_c ? (Wc1 + lane * 64) : (Wr1 + (lane - 48) * 64);
        #pragma unroll
        for (int k = 0; k < 32; ++k) {
            h2 v; v.x = (_Float16)p1[2*k]; v.y = (_Float16)p1[2*k + 1];
            w1p[k] = v;
        }
        const float* p2 = is_c ? (Wc2 + lane * 48) : (Wr2 + (lane - 48) * 16);
        #pragma unroll
        for (int k = 0; k < 24; ++k) {
            const bool valid = is_c || (k >= 16);          // r-lanes: last 8 pairs real
            const int  kk    = is_c ? 2*k : (k >= 16 ? 2*k - 32 : 0);
            h2 v;
            v.x = valid ? (_Float16)p2[kk]     : (_Float16)0.0f;
            v.y = valid ? (_Float16)p2[kk + 1] : (_Float16)0.0f;
            w2p[k] = v;
        }
        b1 = is_c ? bc1[lane] : br1[lane - 48];
        b2 = is_c ? bc2[lane] : br2[lane - 48];
    }
    // layer-2 input window in h8 units: c-lanes read u feats 0..47 (h8 0..5),
    // r-lanes read feats 16..63 (h8 2..7) with w2p[0..15] zeroed.
    const int   ub8 = is_c ? 0 : 2;
    const float sgn = (lane & 1) ? 1.0f : -1.0f;
    const bool  odd = (lane & 1) != 0;

    // ---- init state ----
    float ysel = x[blk * 64 + lane];
    _Float16* py = (_Float16*)lds_y8;
    _Float16* pu = (_Float16*)lds_u8;
    py[lane] = (_Float16)ysel;
    float* pout = out + (size_t)blk * (TSTEP * 64) + lane;

    // Single-wave workgroup, wave-synchronous LDS (in-order DS pipe): no barriers.
    for (int t = 0; t < TSTEP; ++t) {
        // ---- layer 1: u = tanh(W1 @ y + b1); v_dot2_f32_f16, 4 chains ----
        float a0 = b1, a1 = 0.0f, a2 = 0.0f, a3 = 0.0f;
        #pragma unroll
        for (int k = 0; k < 8; ++k) {
            const h8 q = lds_y8[k];                        // uniform ds_read_b128
            a0 = __builtin_amdgcn_fdot2(w1p[4*k + 0], __builtin_shufflevector(q, q, 0, 1), a0, false);
            a1 = __builtin_amdgcn_fdot2(w1p[4*k + 1], __builtin_shufflevector(q, q, 2, 3), a1, false);
            a2 = __builtin_amdgcn_fdot2(w1p[4*k + 2], __builtin_shufflevector(q, q, 4, 5), a2, false);
            a3 = __builtin_amdgcn_fdot2(w1p[4*k + 3], __builtin_shufflevector(q, q, 6, 7), a3, false);
        }
        const float u = fast_tanh((a0 + a1) + (a2 + a3));
        pu[lane] = (_Float16)u;                            // ds_write_b16

        // ---- layer 2: co/re = W2 @ u + b2 ----
        float c0 = b2, c1 = 0.0f, c2 = 0.0f, c3 = 0.0f;
        #pragma unroll
        for (int k = 0; k < 6; ++k) {
            const h8 q = lds_u8[ub8 + k];
            c0 = __builtin_amdgcn_fdot2(w2p[4*k + 0], __builtin_shufflevector(q, q, 0, 1), c0, false);
            c1 = __builtin_amdgcn_fdot2(w2p[4*k + 1], __builtin_shufflevector(q, q, 2, 3), c1, false);
            c2 = __builtin_amdgcn_fdot2(w2p[4*k + 2], __builtin_shufflevector(q, q, 4, 5), c2, false);
            c3 = __builtin_amdgcn_fdot2(w2p[4*k + 3], __builtin_shufflevector(q, q, 6, 7), c3, false);
        }
        const float co = (c0 + c1) + (c2 + c3);

        // ---- pointwise update (all fp32) ----
        const float other = __shfl_xor(co, 1, 64);
        const float mu = odd ? other : co;     // even slot of pair
        const float om = odd ? co    : other;  // odd slot of pair
        const float scale = fast_exp(DTC * mu);
        const float omr = om * 1.59154943e-3f; // dt*om/(2*pi): v_sin takes revolutions
        const float sv = __builtin_amdgcn_sinf(omr) * scale;
        const float cv = __builtin_amdgcn_cosf(omr) * scale;
        const float yo = __shfl_xor(ysel, 1, 64);
        // even lane: c*y_self - s*y_partner ; odd lane: c*y_self + s*y_partner
        const float ycnew = fmaf(cv, ysel, sgn * sv * yo);
        const float yrnew = fast_exp(DTC * co) * ysel;
        const float ynew  = is_c ? ycnew : yrnew;
        ysel = ynew;
        py[lane] = (_Float16)ynew;             // f16 broadcast copy only
        __builtin_nontemporal_store(ynew, pout);
        pout += 64;
    }
}

extern "C" void kernel_launch(void* const* d_in, const int* in_sizes, int n_in,
                              void* d_out, int out_size, void* d_ws, size_t ws_size,
                              hipStream_t stream) {
    const float* x   = (const float*)d_in[0];
    const float* Wc1 = (const float*)d_in[1];
    const float* bc1 = (const float*)d_in[2];
    const float* Wc2 = (const float*)d_in[3];
    const float* bc2 = (const float*)d_in[4];
    const float* Wr1 = (const float*)d_in[5];
    const float* br1 = (const float*)d_in[6];
    const float* Wr2 = (const float*)d_in[7];
    const float* br2 = (const float*)d_in[8];
    float* out = (float*)d_out;

    koopman_kernel<<<dim3(NB), dim3(64), 0, stream>>>(
        x, Wc1, bc1, Wc2, bc2, Wr1, br1, Wr2, br2, out);
}